// Round 4
// baseline (138.784 us; speedup 1.0000x reference)
//
#include <hip/hip_runtime.h>
#include <hip/hip_bf16.h>

// Problem sizes (fixed)
#define BB   16
#define SS   32
#define TKK  128
#define NN   512
#define LPB  4096            // S*TK rows per batch
#define RPB  64              // rows per score-kernel block

using bf16x8 = __attribute__((ext_vector_type(8))) __bf16;
using f32x4  = __attribute__((ext_vector_type(4))) float;

__device__ inline unsigned pack_bf16(float a, float b) {
  unsigned ua = __float_as_uint(a);
  unsigned ub = __float_as_uint(b);
  ua = (ua + 0x7FFFu + ((ua >> 16) & 1u)) >> 16;   // RNE
  ub = (ub + 0x7FFFu + ((ub >> 16) & 1u)) >> 16;
  return ua | (ub << 16);
}

__device__ inline float tanh_fast(float x) {
  // tanh(x) = 1 - 2/(e^{2x}+1); stable at both extremes
  float e = __expf(2.0f * x);
  return 1.0f - 2.0f * __builtin_amdgcn_rcpf(e + 1.0f);
}

// Fragment-layout helpers.
// Frag index for (row-tile rt, k-slice ks, lane): (rt*16+ks)*64 + lane,
// where lane = lh*16 + lr; covers global k = ks*32 + lh*4 + {0..3, 16..19},
// row = rt*16 + lr. swz() is an involution spreading LDS banks.
__device__ inline int swz(int f) { return f ^ ((f >> 4) & 15); }

// ---------------------------------------------------------------------------
// Merged prep (512-thread blocks):
//  blocks [0,8):  repack W_h (fp32 [m][k]) -> bf16 B-frag order via LDS
//                 (coalesced global read, swizzled LDS, coalesced global write)
//  blocks [8,24): dec_fea = s_t_hat @ W_d^T + b_d
// ---------------------------------------------------------------------------
__global__ __launch_bounds__(512)
void prep_kernel(const float* __restrict__ W_h, uint4* __restrict__ Wpack,
                 const float* __restrict__ s_t_hat,
                 const float* __restrict__ W_d,
                 const float* __restrict__ b_d,
                 float* __restrict__ decfea) {
  __shared__ __align__(16) uint4 Wf[4096];     // 64 KiB
  int tid = threadIdx.x;
  if (blockIdx.x < 8) {
    int tile = blockIdx.x;                     // 64 m-rows per tile
    const float4* wblk = reinterpret_cast<const float4*>(W_h + (size_t)tile * 64 * NN);
    #pragma unroll
    for (int i = 0; i < 8; ++i) {
      int u   = i * 512 + tid;                 // frag id in [0,4096)
      int row = u >> 6;                        // m within tile
      int ks  = (u >> 2) & 15;
      int lh  = u & 3;
      int fb  = row * 128 + ks * 8 + lh;       // float4 index
      float4 h0 = wblk[fb];
      float4 h1 = wblk[fb + 4];                // +16 floats
      int frag = ((row >> 4) * 16 + ks) * 64 + lh * 16 + (row & 15);
      uint4 o;
      o.x = pack_bf16(h0.x, h0.y); o.y = pack_bf16(h0.z, h0.w);
      o.z = pack_bf16(h1.x, h1.y); o.w = pack_bf16(h1.z, h1.w);
      Wf[swz(frag)] = o;
    }
    __syncthreads();
    #pragma unroll
    for (int i = 0; i < 8; ++i) {
      int f = i * 512 + tid;
      Wpack[tile * 4096 + f] = Wf[swz(f)];
    }
  } else {
    int idx = (blockIdx.x - 8) * 512 + tid;    // 8192 total
    int b = idx >> 9, m = idx & 511;
    const float4* sp = reinterpret_cast<const float4*>(s_t_hat + b * NN);
    const float4* wp = reinterpret_cast<const float4*>(W_d + m * NN);
    float acc = 0.f;
    #pragma unroll 8
    for (int i = 0; i < NN / 4; ++i) {
      float4 a = sp[i], w = wp[i];
      acc += a.x * w.x + a.y * w.y + a.z * w.z + a.w * w.w;
    }
    decfea[idx] = acc + b_d[m];
  }
}

// ---------------------------------------------------------------------------
// Main fused kernel: per 64-row tile, E = h @ W_h^T via bf16 MFMA (fp32 acc),
// then score = v . tanh(E + dec_fea + cov*W_c), weighted = beta * score.
// 512 threads = 8 waves; wave w owns m-tiles [w*4, w*4+4).
// Staging: fully-coalesced global float4 reads (wave = contiguous 2-KB row),
// frag permutation done in LDS with XOR-swizzled ds_write_b128.
// ---------------------------------------------------------------------------
__global__ __launch_bounds__(512, 4)
void score_kernel(const float* __restrict__ h,
                  const float* __restrict__ coverage,
                  const float* __restrict__ beta,
                  const float* __restrict__ W_c,
                  const float* __restrict__ v,
                  const uint4* __restrict__ Wpack,
                  const float* __restrict__ decfea,
                  float* __restrict__ weighted) {
  __shared__ __align__(16) unsigned short Afrag[RPB * NN];   // 64 KiB
  int tid  = threadIdx.x;
  int rb   = blockIdx.x;                 // 1024 blocks
  int bidx = rb >> 6;                    // 64 blocks per batch
  const float4* hblk4 = reinterpret_cast<const float4*>(h + (size_t)rb * RPB * NN);

  // ---- stage h tile -> bf16 frag-ordered (swizzled) LDS ----
  uint4* Af4 = reinterpret_cast<uint4*>(Afrag);
  #pragma unroll
  for (int i = 0; i < 8; ++i) {
    int u   = i * 512 + tid;             // frag id, 4096 total
    int row = u >> 6;
    int ks  = (u >> 2) & 15;
    int lh  = u & 3;
    int fb  = row * 128 + ks * 8 + lh;   // float4 index (coalesced per wave)
    float4 h0 = hblk4[fb];
    float4 h1 = hblk4[fb + 4];
    int frag = ((row >> 4) * 16 + ks) * 64 + lh * 16 + (row & 15);
    uint4 o;
    o.x = pack_bf16(h0.x, h0.y); o.y = pack_bf16(h0.z, h0.w);
    o.z = pack_bf16(h1.x, h1.y); o.w = pack_bf16(h1.z, h1.w);
    Af4[swz(frag)] = o;
  }
  __syncthreads();

  int lane = tid & 63;
  int w    = tid >> 6;                   // wave id, 0..7

  f32x4 acc[4][4];
  const f32x4 zz = {0.f, 0.f, 0.f, 0.f};
  #pragma unroll
  for (int q = 0; q < 4; ++q)
    #pragma unroll
    for (int rt = 0; rt < 4; ++rt) acc[q][rt] = zz;

  const bf16x8* Afv = reinterpret_cast<const bf16x8*>(Afrag);
  const bf16x8* Bv  = reinterpret_cast<const bf16x8*>(Wpack) + (size_t)(w * 4) * 16 * 64 + lane;

  // software-prefetched B: load ks+1 frags while MFMAing ks
  bf16x8 bf[4];
  #pragma unroll
  for (int q = 0; q < 4; ++q)
    bf[q] = Bv[(q * 16 + 0) * 64];
  #pragma unroll 4
  for (int ks = 0; ks < 16; ++ks) {
    bf16x8 af[4];
    #pragma unroll
    for (int rt = 0; rt < 4; ++rt) {
      int f = (rt * 16 + ks) * 64 + lane;
      af[rt] = Afv[swz(f)];
    }
    bf16x8 bn[4];
    if (ks < 15) {
      #pragma unroll
      for (int q = 0; q < 4; ++q)
        bn[q] = Bv[(q * 16 + ks + 1) * 64];
    }
    #pragma unroll
    for (int q = 0; q < 4; ++q)
      #pragma unroll
      for (int rt = 0; rt < 4; ++rt)
        acc[q][rt] = __builtin_amdgcn_mfma_f32_16x16x32_bf16(af[rt], bf[q], acc[q][rt], 0, 0, 0);
    #pragma unroll
    for (int q = 0; q < 4; ++q) bf[q] = bn[q];
  }

  // ---- epilogue: + dec_fea + cov*W_c, tanh, v-weighted reduce over m ----
  int col = lane & 15;                   // C/D: col = lane&15
  int rhi = (lane >> 4) << 2;            // row  = (lane>>4)*4 + reg
  float cv[4][4];
  #pragma unroll
  for (int rt = 0; rt < 4; ++rt)
    #pragma unroll
    for (int r = 0; r < 4; ++r)
      cv[rt][r] = coverage[rb * RPB + rt * 16 + rhi + r];

  float sc[4][4] = {};
  #pragma unroll
  for (int q = 0; q < 4; ++q) {
    int m = (w * 4 + q) * 16 + col;
    float dv = decfea[bidx * NN + m];
    float wc = W_c[m];
    float vv = v[m];
    #pragma unroll
    for (int rt = 0; rt < 4; ++rt)
      #pragma unroll
      for (int r = 0; r < 4; ++r) {
        float x = acc[q][rt][r] + dv + cv[rt][r] * wc;
        sc[rt][r] += vv * tanh_fast(x);
      }
  }
  #pragma unroll
  for (int rt = 0; rt < 4; ++rt)
    #pragma unroll
    for (int r = 0; r < 4; ++r) {
      float s = sc[rt][r];
      s += __shfl_xor(s, 1);
      s += __shfl_xor(s, 2);
      s += __shfl_xor(s, 4);
      s += __shfl_xor(s, 8);
      sc[rt][r] = s;
    }

  __syncthreads();                       // Afrag reads done; reuse as scorebuf
  float* scorebuf = reinterpret_cast<float*>(Afrag);   // [8][64]
  if (col == 0) {
    #pragma unroll
    for (int rt = 0; rt < 4; ++rt)
      #pragma unroll
      for (int r = 0; r < 4; ++r)
        scorebuf[w * RPB + rt * 16 + rhi + r] = sc[rt][r];
  }
  __syncthreads();
  if (tid < RPB) {
    float total = 0.f;
    #pragma unroll
    for (int ww = 0; ww < 8; ++ww) total += scorebuf[ww * RPB + tid];
    int gl = rb * RPB + tid;
    int lb = gl & (LPB - 1);
    int s  = lb >> 7;                    // TK = 128
    weighted[bidx * LPB + lb] = beta[bidx * SS + s] * total;
  }
}

// ---------------------------------------------------------------------------
// Softmax over 4096 per batch, mask, renormalize; write attn_dist + coverage_new.
// Also zeroes c_t for the following atomic-accumulate kernel.
// ---------------------------------------------------------------------------
__global__ void softmax_kernel(const float* __restrict__ coverage,
                               const float* __restrict__ mask,
                               float* __restrict__ out) {
  int b = blockIdx.x;
  int t = threadIdx.x;
  float* ct   = out;                     // [0, 8192)
  float* attn = out + 8192;              // weighted in, attn_dist out
  float* covn = out + 8192 + 65536;      // coverage_new

  ct[b * NN + t] = 0.f;
  ct[b * NN + 256 + t] = 0.f;

  float wv[16];
  float mx = -1e30f;
  #pragma unroll
  for (int i = 0; i < 16; ++i) {
    wv[i] = attn[b * LPB + i * 256 + t];
    mx = fmaxf(mx, wv[i]);
  }
  __shared__ float redm[4], reds[4];
  mx = fmaxf(mx, __shfl_xor(mx, 1));
  mx = fmaxf(mx, __shfl_xor(mx, 2));
  mx = fmaxf(mx, __shfl_xor(mx, 4));
  mx = fmaxf(mx, __shfl_xor(mx, 8));
  mx = fmaxf(mx, __shfl_xor(mx, 16));
  mx = fmaxf(mx, __shfl_xor(mx, 32));
  if ((t & 63) == 0) redm[t >> 6] = mx;
  __syncthreads();
  mx = fmaxf(fmaxf(redm[0], redm[1]), fmaxf(redm[2], redm[3]));

  float e[16];
  float sum = 0.f;
  #pragma unroll
  for (int i = 0; i < 16; ++i) {
    e[i] = __expf(wv[i] - mx) * mask[b * LPB + i * 256 + t];
    sum += e[i];
  }
  sum += __shfl_xor(sum, 1);
  sum += __shfl_xor(sum, 2);
  sum += __shfl_xor(sum, 4);
  sum += __shfl_xor(sum, 8);
  sum += __shfl_xor(sum, 16);
  sum += __shfl_xor(sum, 32);
  if ((t & 63) == 0) reds[t >> 6] = sum;
  __syncthreads();
  sum = reds[0] + reds[1] + reds[2] + reds[3];
  float inv = 1.0f / sum;
  #pragma unroll
  for (int i = 0; i < 16; ++i) {
    int l = i * 256 + t;
    float a = e[i] * inv;
    attn[b * LPB + l] = a;
    covn[b * LPB + l] = coverage[b * LPB + l] + a;
  }
}

// ---------------------------------------------------------------------------
// c_t[b][n] = sum_l attn[b][l] * h[b][l][n]  (memory-bound, atomic partials)
// float4 loads: wave reads 1 KB contiguous per instruction.
// ---------------------------------------------------------------------------
__global__ void ct_kernel(const float* __restrict__ h, float* __restrict__ out) {
  int blk   = blockIdx.x;                // 1024
  int b     = blk >> 6;
  int chunk = blk & 63;
  int t     = threadIdx.x;               // 256
  const float* attn = out + 8192 + b * LPB + chunk * 64;
  __shared__ float as_[64];
  if (t < 64) as_[t] = attn[t];
  __syncthreads();
  int cg = t & 127;                      // col-group of 4 floats
  int r0 = t >> 7;                       // 0 or 1
  const float4* hp = reinterpret_cast<const float4*>(h + (size_t)(b * LPB + chunk * 64) * NN);
  float ax = 0.f, ay = 0.f, az = 0.f, aw = 0.f;
  #pragma unroll 8
  for (int r = r0; r < 64; r += 2) {
    float4 hv = hp[r * 128 + cg];
    float av = as_[r];
    ax += av * hv.x; ay += av * hv.y; az += av * hv.z; aw += av * hv.w;
  }
  atomicAdd(&out[b * NN + cg * 4 + 0], ax);
  atomicAdd(&out[b * NN + cg * 4 + 1], ay);
  atomicAdd(&out[b * NN + cg * 4 + 2], az);
  atomicAdd(&out[b * NN + cg * 4 + 3], aw);
}

extern "C" void kernel_launch(void* const* d_in, const int* in_sizes, int n_in,
                              void* d_out, int out_size, void* d_ws, size_t ws_size,
                              hipStream_t stream) {
  const float* s_t_hat  = (const float*)d_in[0];
  const float* h        = (const float*)d_in[1];
  const float* coverage = (const float*)d_in[2];
  const float* mask     = (const float*)d_in[3];
  const float* beta     = (const float*)d_in[4];
  const float* W_h      = (const float*)d_in[5];
  const float* W_c      = (const float*)d_in[6];
  const float* W_d      = (const float*)d_in[7];
  const float* b_d      = (const float*)d_in[8];
  const float* v        = (const float*)d_in[9];
  float* out = (float*)d_out;

  uint4* Wpack    = (uint4*)d_ws;           // 512 KiB
  float* decfea   = out + 8192 + 65536;     // staged in coverage_new region
  float* weighted = out + 8192;             // staged in attn_dist region

  prep_kernel <<<24, 512, 0, stream>>>(W_h, Wpack, s_t_hat, W_d, b_d, decfea);
  score_kernel<<<1024, 512, 0, stream>>>(h, coverage, beta, W_c, v, Wpack, decfea, weighted);
  softmax_kernel<<<16, 256, 0, stream>>>(coverage, mask, out);
  ct_kernel<<<1024, 256, 0, stream>>>(h, out);
}

// Round 5
// 134.137 us; speedup vs baseline: 1.0346x; 1.0346x over previous
//
#include <hip/hip_runtime.h>
#include <hip/hip_bf16.h>

// Problem sizes (fixed)
#define BB   16
#define SS   32
#define TKK  128
#define NN   512
#define LPB  4096            // S*TK rows per batch
#define RPB  64              // rows per score-kernel block

using bf16x8 = __attribute__((ext_vector_type(8))) __bf16;
using f32x4  = __attribute__((ext_vector_type(4))) float;

__device__ inline unsigned pack_bf16(float a, float b) {
  unsigned ua = __float_as_uint(a);
  unsigned ub = __float_as_uint(b);
  ua = (ua + 0x7FFFu + ((ua >> 16) & 1u)) >> 16;   // RNE
  ub = (ub + 0x7FFFu + ((ub >> 16) & 1u)) >> 16;
  return ua | (ub << 16);
}

__device__ inline float tanh_fast(float x) {
  // tanh(x) = 1 - 2/(e^{2x}+1); stable at both extremes
  float e = __expf(2.0f * x);
  return 1.0f - 2.0f * __builtin_amdgcn_rcpf(e + 1.0f);
}

// Fragment-layout helpers.
// Frag index for (row-tile rt, k-slice ks, lane): (rt*16+ks)*64 + lane,
// where lane = lh*16 + lr; covers global k = ks*32 + lh*4 + {0..3, 16..19},
// row = rt*16 + lr. swz() is an involution spreading LDS banks.
__device__ inline int swz(int f) { return f ^ ((f >> 4) & 15); }

// ---------------------------------------------------------------------------
// Merged prep (512-thread blocks):
//  blocks [0,8):  repack W_h (fp32 [m][k]) -> bf16 B-frag order via LDS
//  blocks [8,24): dec_fea = s_t_hat @ W_d^T + b_d
// ---------------------------------------------------------------------------
__global__ __launch_bounds__(512)
void prep_kernel(const float* __restrict__ W_h, uint4* __restrict__ Wpack,
                 const float* __restrict__ s_t_hat,
                 const float* __restrict__ W_d,
                 const float* __restrict__ b_d,
                 float* __restrict__ decfea) {
  __shared__ __align__(16) uint4 Wf[4096];     // 64 KiB
  int tid = threadIdx.x;
  if (blockIdx.x < 8) {
    int tile = blockIdx.x;                     // 64 m-rows per tile
    const float4* wblk = reinterpret_cast<const float4*>(W_h + (size_t)tile * 64 * NN);
    #pragma unroll
    for (int i = 0; i < 8; ++i) {
      int u   = i * 512 + tid;                 // frag id in [0,4096)
      int row = u >> 6;                        // m within tile
      int ks  = (u >> 2) & 15;
      int lh  = u & 3;
      int fb  = row * 128 + ks * 8 + lh;       // float4 index
      float4 h0 = wblk[fb];
      float4 h1 = wblk[fb + 4];                // +16 floats
      int frag = ((row >> 4) * 16 + ks) * 64 + lh * 16 + (row & 15);
      uint4 o;
      o.x = pack_bf16(h0.x, h0.y); o.y = pack_bf16(h0.z, h0.w);
      o.z = pack_bf16(h1.x, h1.y); o.w = pack_bf16(h1.z, h1.w);
      Wf[swz(frag)] = o;
    }
    __syncthreads();
    #pragma unroll
    for (int i = 0; i < 8; ++i) {
      int f = i * 512 + tid;
      Wpack[tile * 4096 + f] = Wf[swz(f)];
    }
  } else {
    int idx = (blockIdx.x - 8) * 512 + tid;    // 8192 total
    int b = idx >> 9, m = idx & 511;
    const float4* sp = reinterpret_cast<const float4*>(s_t_hat + b * NN);
    const float4* wp = reinterpret_cast<const float4*>(W_d + m * NN);
    float acc = 0.f;
    #pragma unroll 8
    for (int i = 0; i < NN / 4; ++i) {
      float4 a = sp[i], w = wp[i];
      acc += a.x * w.x + a.y * w.y + a.z * w.z + a.w * w.w;
    }
    decfea[idx] = acc + b_d[m];
  }
}

// ---------------------------------------------------------------------------
// Main fused kernel. 512 threads = 8 waves; wave w owns m-tiles [w*4, w*4+4).
// Inner loop: statically-unrolled software pipeline — B global prefetch depth
// 2 (3-buffer rotation), A ds_read prefetch depth 1 (2-buffer). All buffer
// indices are compile-time constants (no scratch).
// ---------------------------------------------------------------------------
__global__ __launch_bounds__(512, 4)
void score_kernel(const float* __restrict__ h,
                  const float* __restrict__ coverage,
                  const float* __restrict__ beta,
                  const float* __restrict__ W_c,
                  const float* __restrict__ v,
                  const uint4* __restrict__ Wpack,
                  const float* __restrict__ decfea,
                  float* __restrict__ weighted) {
  __shared__ __align__(16) unsigned short Afrag[RPB * NN];   // 64 KiB
  int tid  = threadIdx.x;
  int rb   = blockIdx.x;                 // 1024 blocks
  int bidx = rb >> 6;                    // 64 blocks per batch
  const float4* hblk4 = reinterpret_cast<const float4*>(h + (size_t)rb * RPB * NN);

  // ---- stage h tile -> bf16 frag-ordered (swizzled) LDS ----
  uint4* Af4 = reinterpret_cast<uint4*>(Afrag);
  #pragma unroll
  for (int i = 0; i < 8; ++i) {
    int u   = i * 512 + tid;             // frag id, 4096 total
    int row = u >> 6;
    int ks  = (u >> 2) & 15;
    int lh  = u & 3;
    int fb  = row * 128 + ks * 8 + lh;   // float4 index (coalesced per wave)
    float4 h0 = hblk4[fb];
    float4 h1 = hblk4[fb + 4];
    int frag = ((row >> 4) * 16 + ks) * 64 + lh * 16 + (row & 15);
    uint4 o;
    o.x = pack_bf16(h0.x, h0.y); o.y = pack_bf16(h0.z, h0.w);
    o.z = pack_bf16(h1.x, h1.y); o.w = pack_bf16(h1.z, h1.w);
    Af4[swz(frag)] = o;
  }

  int lane = tid & 63;
  int w    = tid >> 6;                   // wave id, 0..7
  int col  = lane & 15;                  // C/D: col = lane&15
  int rhi  = (lane >> 4) << 2;           // row  = (lane>>4)*4 + reg

  // ---- hoist epilogue operands (independent of LDS) ----
  float cv[4][4];
  #pragma unroll
  for (int rt = 0; rt < 4; ++rt)
    #pragma unroll
    for (int r = 0; r < 4; ++r)
      cv[rt][r] = coverage[rb * RPB + rt * 16 + rhi + r];
  float dv[4], wc[4], vv[4];
  #pragma unroll
  for (int q = 0; q < 4; ++q) {
    int m = (w * 4 + q) * 16 + col;
    dv[q] = decfea[bidx * NN + m];
    wc[q] = W_c[m];
    vv[q] = v[m];
  }

  __syncthreads();

  f32x4 acc[4][4];
  const f32x4 zz = {0.f, 0.f, 0.f, 0.f};
  #pragma unroll
  for (int q = 0; q < 4; ++q)
    #pragma unroll
    for (int rt = 0; rt < 4; ++rt) acc[q][rt] = zz;

  const bf16x8* Afv = reinterpret_cast<const bf16x8*>(Afrag);
  const bf16x8* Bv  = reinterpret_cast<const bf16x8*>(Wpack) + (size_t)(w * 4) * 16 * 64 + lane;

  // ---- software pipeline: B depth-2 (3 bufs), A depth-1 (2 bufs) ----
  bf16x8 bb[3][4];
  bf16x8 ab[2][4];
  #pragma unroll
  for (int q = 0; q < 4; ++q) bb[0][q] = Bv[(q * 16 + 0) * 64];
  #pragma unroll
  for (int q = 0; q < 4; ++q) bb[1][q] = Bv[(q * 16 + 1) * 64];
  #pragma unroll
  for (int rt = 0; rt < 4; ++rt) ab[0][rt] = Afv[swz((rt * 16 + 0) * 64 + lane)];

  #pragma unroll
  for (int ks = 0; ks < 16; ++ks) {
    const int cb = ks % 3;               // current B buffer
    const int pb = (ks + 2) % 3;         // B buffer being filled (for ks+2)
    const int ca = ks & 1;               // current A buffer
    const int pa = ca ^ 1;               // A buffer being filled (for ks+1)
    if (ks + 2 < 16) {
      #pragma unroll
      for (int q = 0; q < 4; ++q)
        bb[pb][q] = Bv[(q * 16 + ks + 2) * 64];
    }
    if (ks + 1 < 16) {
      #pragma unroll
      for (int rt = 0; rt < 4; ++rt)
        ab[pa][rt] = Afv[swz((rt * 16 + ks + 1) * 64 + lane)];
    }
    #pragma unroll
    for (int q = 0; q < 4; ++q)
      #pragma unroll
      for (int rt = 0; rt < 4; ++rt)
        acc[q][rt] = __builtin_amdgcn_mfma_f32_16x16x32_bf16(ab[ca][rt], bb[cb][q], acc[q][rt], 0, 0, 0);
  }

  // ---- epilogue: + dec_fea + cov*W_c, tanh, v-weighted reduce over m ----
  float sc[4][4] = {};
  #pragma unroll
  for (int q = 0; q < 4; ++q) {
    #pragma unroll
    for (int rt = 0; rt < 4; ++rt)
      #pragma unroll
      for (int r = 0; r < 4; ++r) {
        float x = acc[q][rt][r] + dv[q] + cv[rt][r] * wc[q];
        sc[rt][r] += vv[q] * tanh_fast(x);
      }
  }
  #pragma unroll
  for (int rt = 0; rt < 4; ++rt)
    #pragma unroll
    for (int r = 0; r < 4; ++r) {
      float s = sc[rt][r];
      s += __shfl_xor(s, 1);
      s += __shfl_xor(s, 2);
      s += __shfl_xor(s, 4);
      s += __shfl_xor(s, 8);
      sc[rt][r] = s;
    }

  __syncthreads();                       // Afrag reads done; reuse as scorebuf
  float* scorebuf = reinterpret_cast<float*>(Afrag);   // [8][64]
  if (col == 0) {
    #pragma unroll
    for (int rt = 0; rt < 4; ++rt)
      #pragma unroll
      for (int r = 0; r < 4; ++r)
        scorebuf[w * RPB + rt * 16 + rhi + r] = sc[rt][r];
  }
  __syncthreads();
  if (tid < RPB) {
    float total = 0.f;
    #pragma unroll
    for (int ww = 0; ww < 8; ++ww) total += scorebuf[ww * RPB + tid];
    int gl = rb * RPB + tid;
    int lb = gl & (LPB - 1);
    int s  = lb >> 7;                    // TK = 128
    weighted[bidx * LPB + lb] = beta[bidx * SS + s] * total;
  }
}

// ---------------------------------------------------------------------------
// Softmax over 4096 per batch, mask, renormalize; write attn_dist + coverage_new.
// Also zeroes c_t for the following atomic-accumulate kernel.
// ---------------------------------------------------------------------------
__global__ void softmax_kernel(const float* __restrict__ coverage,
                               const float* __restrict__ mask,
                               float* __restrict__ out) {
  int b = blockIdx.x;
  int t = threadIdx.x;
  float* ct   = out;                     // [0, 8192)
  float* attn = out + 8192;              // weighted in, attn_dist out
  float* covn = out + 8192 + 65536;      // coverage_new

  ct[b * NN + t] = 0.f;
  ct[b * NN + 256 + t] = 0.f;

  float wv[16];
  float mx = -1e30f;
  #pragma unroll
  for (int i = 0; i < 16; ++i) {
    wv[i] = attn[b * LPB + i * 256 + t];
    mx = fmaxf(mx, wv[i]);
  }
  __shared__ float redm[4], reds[4];
  mx = fmaxf(mx, __shfl_xor(mx, 1));
  mx = fmaxf(mx, __shfl_xor(mx, 2));
  mx = fmaxf(mx, __shfl_xor(mx, 4));
  mx = fmaxf(mx, __shfl_xor(mx, 8));
  mx = fmaxf(mx, __shfl_xor(mx, 16));
  mx = fmaxf(mx, __shfl_xor(mx, 32));
  if ((t & 63) == 0) redm[t >> 6] = mx;
  __syncthreads();
  mx = fmaxf(fmaxf(redm[0], redm[1]), fmaxf(redm[2], redm[3]));

  float e[16];
  float sum = 0.f;
  #pragma unroll
  for (int i = 0; i < 16; ++i) {
    e[i] = __expf(wv[i] - mx) * mask[b * LPB + i * 256 + t];
    sum += e[i];
  }
  sum += __shfl_xor(sum, 1);
  sum += __shfl_xor(sum, 2);
  sum += __shfl_xor(sum, 4);
  sum += __shfl_xor(sum, 8);
  sum += __shfl_xor(sum, 16);
  sum += __shfl_xor(sum, 32);
  if ((t & 63) == 0) reds[t >> 6] = sum;
  __syncthreads();
  sum = reds[0] + reds[1] + reds[2] + reds[3];
  float inv = 1.0f / sum;
  #pragma unroll
  for (int i = 0; i < 16; ++i) {
    int l = i * 256 + t;
    float a = e[i] * inv;
    attn[b * LPB + l] = a;
    covn[b * LPB + l] = coverage[b * LPB + l] + a;
  }
}

// ---------------------------------------------------------------------------
// c_t[b][n] = sum_l attn[b][l] * h[b][l][n]  (memory-bound, atomic partials)
// R3-proven version: float2 loads, one atomic per distinct address.
// ---------------------------------------------------------------------------
__global__ void ct_kernel(const float* __restrict__ h, float* __restrict__ out) {
  int blk   = blockIdx.x;                // 1024
  int b     = blk >> 6;
  int chunk = blk & 63;
  int t     = threadIdx.x;
  const float* attn = out + 8192 + b * LPB + chunk * 64;
  __shared__ float as_[64];
  if (t < 64) as_[t] = attn[t];
  __syncthreads();
  const float* hp = h + (size_t)(b * LPB + chunk * 64) * NN;
  float a0 = 0.f, a1 = 0.f;
  #pragma unroll 4
  for (int r = 0; r < 64; ++r) {
    float2 hv = *reinterpret_cast<const float2*>(hp + r * NN + t * 2);
    float av = as_[r];
    a0 += av * hv.x;
    a1 += av * hv.y;
  }
  atomicAdd(&out[b * NN + t * 2],     a0);
  atomicAdd(&out[b * NN + t * 2 + 1], a1);
}

extern "C" void kernel_launch(void* const* d_in, const int* in_sizes, int n_in,
                              void* d_out, int out_size, void* d_ws, size_t ws_size,
                              hipStream_t stream) {
  const float* s_t_hat  = (const float*)d_in[0];
  const float* h        = (const float*)d_in[1];
  const float* coverage = (const float*)d_in[2];
  const float* mask     = (const float*)d_in[3];
  const float* beta     = (const float*)d_in[4];
  const float* W_h      = (const float*)d_in[5];
  const float* W_c      = (const float*)d_in[6];
  const float* W_d      = (const float*)d_in[7];
  const float* b_d      = (const float*)d_in[8];
  const float* v        = (const float*)d_in[9];
  float* out = (float*)d_out;

  uint4* Wpack    = (uint4*)d_ws;           // 512 KiB
  float* decfea   = out + 8192 + 65536;     // staged in coverage_new region
  float* weighted = out + 8192;             // staged in attn_dist region

  prep_kernel <<<24, 512, 0, stream>>>(W_h, Wpack, s_t_hat, W_d, b_d, decfea);
  score_kernel<<<1024, 512, 0, stream>>>(h, coverage, beta, W_c, v, Wpack, decfea, weighted);
  softmax_kernel<<<16, 256, 0, stream>>>(coverage, mask, out);
  ct_kernel<<<1024, 256, 0, stream>>>(h, out);
}